// Round 4
// baseline (289.671 us; speedup 1.0000x reference)
//
#include <hip/hip_runtime.h>
#include <hip/hip_cooperative_groups.h>

namespace cg = cooperative_groups;

// DIN attention unit, MI355X — round 10: 4 blocks/CU cooperative.
// R9 post-mortem: fusion correct but dur 246us > split sum (~195us);
// VALUBusy fell to 35%. Cause: coop grid 512 blocks = 2/CU = 8 waves/CU
// (22% occ) locked in latency-bound regime + ~50us grid.sync idle.
// Fix: 1024 coop blocks (2 per batch, 4/CU -> 16 waves/CU) with register
// diet to fit: NPOS 4->2 (kk 80->40 VGPR, h1 64->32), launch_bounds(256,4)
// pins allocator <=128 VGPR. prep_kernel now also zeroes ws+out (2
// dispatches total). Cross-block ws readback stays AGENT-scope atomic
// (R9 correctness fix). Weights stay on scalar path (R7 win).
// mask input UNUSED (reference uses unmasked scores — reproduced bug).

#define BB 512
#define TT 2048
#define DD 20
#define C0 32
#define C1 16

#define NTH 256               // 4 waves/block
#define NPOS 2                // positions per register round (VGPR diet)
#define POSB (NTH * NPOS)     // 512 positions per round
#define CHUNK 1024            // positions per block
#define NROUND (CHUNK / POSB) // 2 rounds
#define NBLK (TT / CHUNK)     // 2 blocks per batch
#define GRID (BB * NBLK)      // 1024 blocks
#define NSLOT 8               // atomic slot-split

// ws float offsets
#define WS_P1 0              // 8 slots * (32 sum + 32 sq)
#define WS_P2 512            // 8 slots * (16 sum + 16 sq)
#define WS_ZERO_N 768        // floats to zero each launch
#define WS_BLOB 896
#define BLOB_J 24            // 20 wM + c + pad
#define BLOB_B (C0 * BLOB_J) // 768 floats per batch

#define PIN(x) asm volatile("" : "+v"(x))
#define AGLOAD(p) \
    __hip_atomic_load((p), __ATOMIC_RELAXED, __HIP_MEMORY_SCOPE_AGENT)

__device__ __forceinline__ float fast_sigmoid(float x) {
    return __builtin_amdgcn_rcpf(1.0f + __expf(-x));
}

__device__ __forceinline__ void load_krow(const float* __restrict__ row,
                                          float* kk) {
    const float4* kr = (const float4*)row;  // rows are 80B => 16B aligned
    float4 a = kr[0], b = kr[1], c = kr[2], d = kr[3], e = kr[4];
    kk[0] = a.x; kk[1] = a.y; kk[2] = a.z; kk[3] = a.w;
    kk[4] = b.x; kk[5] = b.y; kk[6] = b.z; kk[7] = b.w;
    kk[8] = c.x; kk[9] = c.y; kk[10] = c.z; kk[11] = c.w;
    kk[12] = d.x; kk[13] = d.y; kk[14] = d.z; kk[15] = d.w;
    kk[16] = e.x; kk[17] = e.y; kk[18] = e.z; kk[19] = e.w;
}

// ---------------- prep: fold query into layer-1 weights ----------------
// Also zeroes the ws sums area and the output (replaces two memsets).
__global__ void prep_kernel(const float* __restrict__ query,
                            const float* __restrict__ W0,
                            const float* __restrict__ b0,
                            float* __restrict__ blob, float* __restrict__ ws,
                            float* __restrict__ out) {
    const int b = blockIdx.x * 2 + (threadIdx.x >> 5);
    const int j = threadIdx.x & 31;
    if (blockIdx.x == 0) {
        for (int i = threadIdx.x; i < WS_ZERO_N; i += 64) ws[i] = 0.f;
    }
    if (j < DD) out[b * DD + j] = 0.f;
    float cj = b0[j];
    float* dst = blob + (size_t)b * BLOB_B + j * BLOB_J;
#pragma unroll
    for (int d = 0; d < DD; ++d) {
        float w_q = W0[d * C0 + j];
        float w_k = W0[(DD + d) * C0 + j];
        float w_d = W0[(2 * DD + d) * C0 + j];
        float w_p = W0[(3 * DD + d) * C0 + j];
        float qd = query[b * DD + d];
        dst[d] = w_k - w_d + qd * w_p;
        cj = fmaf(qd, w_q + w_d, cj);
    }
    dst[20] = cj;
}

// Load NPOS key rows for round r and PIN them (defeat rematerialization).
#define LOAD_AND_PIN_KEYS(r)                                                 \
    float kk[NPOS][DD];                                                      \
    _Pragma("unroll") for (int pp = 0; pp < NPOS; ++pp)                      \
        load_krow(kbase + (size_t)((r)*POSB + tid + pp * NTH) * DD, kk[pp]); \
    _Pragma("unroll") for (int pp = 0; pp < NPOS; ++pp)                      \
        _Pragma("unroll") for (int d = 0; d < DD; ++d) PIN(kk[pp][d]);

// j-loop over 32 layer-1 channels. Weights on scalar path; scale/shift
// from LDS (uniform broadcast ds_read_b64).
#define TOWER_JLOOP()                                                        \
    _Pragma("unroll 1") for (int j = 0; j < C0; ++j) {                       \
        const float* wr = bA + j * BLOB_J;                                   \
        const float* ur = W1 + j * C1;                                       \
        const float cj = wr[20];                                             \
        const float2 ss = lss0[j];                                           \
        const float al = a0[j];                                              \
        const float nal = 1.0f - al;                                         \
        float h[NPOS];                                                       \
        _Pragma("unroll") for (int pp = 0; pp < NPOS; ++pp) {                \
            float hh = cj;                                                   \
            _Pragma("unroll") for (int d = 0; d < DD; ++d)                   \
                hh = fmaf(kk[pp][d], wr[d], hh);                             \
            h[pp] = hh;                                                      \
        }                                                                    \
        _Pragma("unroll") for (int pp = 0; pp < NPOS; ++pp) {                \
            float pr = fast_sigmoid(fmaf(h[pp], ss.x, ss.y));                \
            float h0d = h[pp] * fmaf(pr, nal, al);                           \
            _Pragma("unroll") for (int c = 0; c < C1; ++c)                   \
                h1[pp][c] = fmaf(h0d, ur[c], h1[pp][c]);                     \
        }                                                                    \
    }

// ================= shared phase bodies =================
__device__ __forceinline__ void phase1_body(int slot, int tid, int lane,
                                            const float* __restrict__ bA,
                                            const float* __restrict__ kbase,
                                            float* __restrict__ ws) {
    float s[C0], q[C0];
#pragma unroll
    for (int j = 0; j < C0; ++j) { s[j] = 0.f; q[j] = 0.f; }
#pragma unroll 1
    for (int r = 0; r < NROUND; ++r) {
        LOAD_AND_PIN_KEYS(r)
#pragma unroll
        for (int j = 0; j < C0; ++j) {
            const float* wr = bA + j * BLOB_J;  // uniform -> s_load
            const float cj = wr[20];
            float sv = 0.f, qv = 0.f;
#pragma unroll
            for (int pp = 0; pp < NPOS; ++pp) {
                float hh = cj;
#pragma unroll
                for (int d = 0; d < DD; ++d) hh = fmaf(kk[pp][d], wr[d], hh);
                sv += hh;
                qv = fmaf(hh, hh, qv);
            }
            s[j] += sv;
            q[j] += qv;
        }
    }
    float redv = 0.f;
#pragma unroll
    for (int v = 0; v < 2 * C0; ++v) {
        float val = (v < C0) ? s[v] : q[v - C0];
#pragma unroll
        for (int o = 32; o >= 1; o >>= 1) val += __shfl_xor(val, o);
        if (lane == v) redv = val;
    }
    atomicAdd(&ws[WS_P1 + slot * (2 * C0) + lane], redv);
}

__device__ __forceinline__ void finalize0(int tid, float* __restrict__ ws,
                                          float2* __restrict__ lss0) {
    if (tid < C0) {
        float sv = 0.f, qv = 0.f;
#pragma unroll
        for (int k = 0; k < NSLOT; ++k) {
            sv += AGLOAD(&ws[WS_P1 + k * (2 * C0) + tid]);
            qv += AGLOAD(&ws[WS_P1 + k * (2 * C0) + C0 + tid]);
        }
        const float invN = 1.0f / (float)(BB * TT);
        float mean = sv * invN;
        float var = qv * invN - mean * mean;
        float sc = rsqrtf(var + 1e-9f);
        lss0[tid] = make_float2(sc, -mean * sc);
    }
}

__device__ __forceinline__ void phase2_body(
    int slot, int tid, int lane, const float* __restrict__ bA,
    const float* __restrict__ kbase, const float* __restrict__ a0,
    const float* __restrict__ W1, const float* __restrict__ b1,
    const float2* __restrict__ lss0, float* __restrict__ ws) {
    float s1[C1], q1[C1];
#pragma unroll
    for (int c = 0; c < C1; ++c) { s1[c] = 0.f; q1[c] = 0.f; }
#pragma unroll 1
    for (int r = 0; r < NROUND; ++r) {
        LOAD_AND_PIN_KEYS(r)
        float h1[NPOS][C1];
#pragma unroll
        for (int pp = 0; pp < NPOS; ++pp)
#pragma unroll
            for (int c = 0; c < C1; ++c) h1[pp][c] = 0.f;
        TOWER_JLOOP()
#pragma unroll
        for (int c = 0; c < C1; ++c) {
            float bc = b1[c];
#pragma unroll
            for (int pp = 0; pp < NPOS; ++pp) {
                float v = h1[pp][c] + bc;
                s1[c] += v;
                q1[c] = fmaf(v, v, q1[c]);
            }
        }
    }
    float redv = 0.f;
#pragma unroll
    for (int v = 0; v < 2 * C1; ++v) {
        float val = (v < C1) ? s1[v] : q1[v - C1];
#pragma unroll
        for (int o = 32; o >= 1; o >>= 1) val += __shfl_xor(val, o);
        if (lane == v) redv = val;
    }
    if (lane < 2 * C1)
        atomicAdd(&ws[WS_P2 + slot * (2 * C1) + lane], redv);
}

__device__ __forceinline__ void finalize1(int tid, float* __restrict__ ws,
                                          const float* __restrict__ a1,
                                          const float* __restrict__ wk,
                                          float4* __restrict__ ld1v) {
    if (tid < C1) {
        float sv = 0.f, qv = 0.f;
#pragma unroll
        for (int k = 0; k < NSLOT; ++k) {
            sv += AGLOAD(&ws[WS_P2 + k * (2 * C1) + tid]);
            qv += AGLOAD(&ws[WS_P2 + k * (2 * C1) + C1 + tid]);
        }
        const float invN = 1.0f / (float)(BB * TT);
        float mean = sv * invN;
        float var = qv * invN - mean * mean;
        float sc = rsqrtf(var + 1e-9f);
        ld1v[tid] = make_float4(sc, -mean * sc, a1[tid], wk[tid]);
    }
}

__device__ __forceinline__ void phase3_body(
    int batch, int tid, int lane, int wave, const float* __restrict__ bA,
    const float* __restrict__ kbase, const float* __restrict__ a0,
    const float* __restrict__ W1, const float* __restrict__ b1,
    const float* __restrict__ bk, const float2* __restrict__ lss0,
    const float4* __restrict__ ld1v, float (*red)[DD],
    float* __restrict__ out) {
    const float bkv = bk[0];
    float oacc[DD];
#pragma unroll
    for (int d = 0; d < DD; ++d) oacc[d] = 0.f;
#pragma unroll 1
    for (int r = 0; r < NROUND; ++r) {
        LOAD_AND_PIN_KEYS(r)
        float h1[NPOS][C1];
#pragma unroll
        for (int pp = 0; pp < NPOS; ++pp)
#pragma unroll
            for (int c = 0; c < C1; ++c) h1[pp][c] = 0.f;
        TOWER_JLOOP()
#pragma unroll
        for (int pp = 0; pp < NPOS; ++pp) {
            float score = bkv;
#pragma unroll
            for (int c = 0; c < C1; ++c) {
                float v = h1[pp][c] + b1[c];
                float4 dv = ld1v[c];
                float pr = fast_sigmoid(fmaf(v, dv.x, dv.y));
                float hd = v * fmaf(pr, 1.0f - dv.z, dv.z);
                score = fmaf(hd, dv.w, score);
            }
#pragma unroll
            for (int d = 0; d < DD; ++d)
                oacc[d] = fmaf(score, kk[pp][d], oacc[d]);
        }
    }
    float redv = 0.f;
#pragma unroll
    for (int v = 0; v < DD; ++v) {
        float val = oacc[v];
#pragma unroll
        for (int o = 32; o >= 1; o >>= 1) val += __shfl_xor(val, o);
        if (lane == v) redv = val;
    }
    if (lane < DD) red[wave][lane] = redv;
    __syncthreads();
    if (tid < DD)
        atomicAdd(&out[batch * DD + tid],
                  red[0][tid] + red[1][tid] + red[2][tid] + red[3][tid]);
}

// ---------------- fused persistent kernel: all 3 passes ----------------
__global__ __launch_bounds__(NTH, 4) void fused_kernel(
    const float* __restrict__ keys, const float* __restrict__ blob,
    const float* __restrict__ a0, const float* __restrict__ W1,
    const float* __restrict__ b1, const float* __restrict__ a1,
    const float* __restrict__ wk, const float* __restrict__ bk,
    float* __restrict__ ws, float* __restrict__ out) {
    const int batch = blockIdx.x >> 1, chunk = blockIdx.x & 1;
    const int slot = blockIdx.x & (NSLOT - 1);
    const int tid = threadIdx.x, wave = tid >> 6, lane = tid & 63;
    const float* bA = blob + (size_t)batch * BLOB_B;
    const float* kbase = keys + ((size_t)batch * TT + chunk * CHUNK) * DD;

    __shared__ float2 lss0[C0];
    __shared__ float4 ld1v[C1];
    __shared__ float red[4][DD];

    phase1_body(slot, tid, lane, bA, kbase, ws);
    cg::this_grid().sync();
    finalize0(tid, ws, lss0);
    __syncthreads();
    phase2_body(slot, tid, lane, bA, kbase, a0, W1, b1, lss0, ws);
    cg::this_grid().sync();
    finalize1(tid, ws, a1, wk, ld1v);
    __syncthreads();
    phase3_body(batch, tid, lane, wave, bA, kbase, a0, W1, b1, bk, lss0,
                ld1v, red, out);
}

// ---------------- split fallback kernels ----------------
__global__ __launch_bounds__(NTH, 4) void pass1_kernel(
    const float* __restrict__ keys, const float* __restrict__ blob,
    float* __restrict__ ws) {
    const int batch = blockIdx.x >> 1, chunk = blockIdx.x & 1;
    const int tid = threadIdx.x, lane = tid & 63;
    phase1_body(blockIdx.x & (NSLOT - 1), tid, lane,
                blob + (size_t)batch * BLOB_B,
                keys + ((size_t)batch * TT + chunk * CHUNK) * DD, ws);
}

__global__ __launch_bounds__(NTH, 4) void pass2_kernel(
    const float* __restrict__ keys, const float* __restrict__ blob,
    const float* __restrict__ a0, const float* __restrict__ W1,
    const float* __restrict__ b1, float* __restrict__ ws) {
    const int batch = blockIdx.x >> 1, chunk = blockIdx.x & 1;
    const int tid = threadIdx.x, lane = tid & 63;
    __shared__ float2 lss0[C0];
    finalize0(tid, ws, lss0);
    __syncthreads();
    phase2_body(blockIdx.x & (NSLOT - 1), tid, lane,
                blob + (size_t)batch * BLOB_B,
                keys + ((size_t)batch * TT + chunk * CHUNK) * DD, a0, W1, b1,
                lss0, ws);
}

__global__ __launch_bounds__(NTH, 4) void pass3_kernel(
    const float* __restrict__ keys, const float* __restrict__ blob,
    const float* __restrict__ a0, const float* __restrict__ W1,
    const float* __restrict__ b1, const float* __restrict__ a1,
    const float* __restrict__ wk, const float* __restrict__ bk,
    float* __restrict__ ws, float* __restrict__ out) {
    const int batch = blockIdx.x >> 1, chunk = blockIdx.x & 1;
    const int tid = threadIdx.x, wave = tid >> 6, lane = tid & 63;
    __shared__ float2 lss0[C0];
    __shared__ float4 ld1v[C1];
    __shared__ float red[4][DD];
    finalize0(tid, ws, lss0);
    finalize1(tid, ws, a1, wk, ld1v);
    __syncthreads();
    phase3_body(batch, tid, lane, wave, blob + (size_t)batch * BLOB_B,
                keys + ((size_t)batch * TT + chunk * CHUNK) * DD, a0, W1, b1,
                bk, lss0, ld1v, red, out);
}

extern "C" void kernel_launch(void* const* d_in, const int* in_sizes, int n_in,
                              void* d_out, int out_size, void* d_ws,
                              size_t ws_size, hipStream_t stream) {
    const float* keys = (const float*)d_in[0];
    const float* query = (const float*)d_in[1];
    // d_in[2] = mask: intentionally unused
    const float* W0 = (const float*)d_in[3];
    const float* b0 = (const float*)d_in[4];
    const float* a0 = (const float*)d_in[5];
    const float* W1 = (const float*)d_in[6];
    const float* b1 = (const float*)d_in[7];
    const float* a1 = (const float*)d_in[8];
    const float* wk = (const float*)d_in[9];
    const float* bk = (const float*)d_in[10];
    float* out = (float*)d_out;
    float* ws = (float*)d_ws;
    float* blob = ws + WS_BLOB;  // 512*768 floats = 1.5 MB scratch
    const float* blobc = blob;

    // prep also zeroes ws sums + out (replaces both memsets)
    prep_kernel<<<BB / 2, 64, 0, stream>>>(query, W0, b0, blob, ws, out);

    // One-time host-side decision: is the 1024-block cooperative grid
    // guaranteed co-resident?
    static int use_coop = -1;
    if (use_coop < 0) {
        int nb = 0, ncu = 0;
        hipError_t e1 = hipOccupancyMaxActiveBlocksPerMultiprocessor(
            &nb, (const void*)fused_kernel, NTH, 0);
        hipDeviceProp_t prop;
        hipError_t e2 = hipGetDeviceProperties(&prop, 0);
        if (e2 == hipSuccess) ncu = prop.multiProcessorCount;
        use_coop = (e1 == hipSuccess && e2 == hipSuccess && nb * ncu >= GRID)
                       ? 1
                       : 0;
    }

    if (use_coop) {
        void* args[] = {(void*)&keys, (void*)&blobc, (void*)&a0, (void*)&W1,
                        (void*)&b1,   (void*)&a1,    (void*)&wk, (void*)&bk,
                        (void*)&ws,   (void*)&out};
        hipError_t e = hipLaunchCooperativeKernel(
            (const void*)fused_kernel, dim3(GRID), dim3(NTH), args, 0,
            stream);
        if (e != hipSuccess) use_coop = 0;  // record failed -> split path
    }
    if (!use_coop) {
        pass1_kernel<<<GRID, NTH, 0, stream>>>(keys, blob, ws);
        pass2_kernel<<<GRID, NTH, 0, stream>>>(keys, blob, a0, W1, b1, ws);
        pass3_kernel<<<GRID, NTH, 0, stream>>>(keys, blob, a0, W1, b1, a1, wk,
                                               bk, ws, out);
    }
}

// Round 5
// 276.952 us; speedup vs baseline: 1.0459x; 1.0459x over previous
//
#include <hip/hip_runtime.h>
#include <hip/hip_cooperative_groups.h>

namespace cg = cooperative_groups;

// DIN attention unit, MI355X — round 11: 1024 coop blocks, allocator freed.
// R10 post-mortem: launch_bounds(256,4) made the allocator pick 64 VGPR
// (not the 128 the bound allows) -> massive scratch spills (WRITE_SIZE
// 0.8->98.8 MB, FETCH +44 MB), VALUBusy 23%. The register diet was never
// needed: R9's fused body fit in 124 VGPR <= 128 under (256,2), i.e.
// 4 waves/SIMD was already register-feasible; R9 was merely GRID-limited
// (512 blocks = 2/CU). Fix: keep 1024 blocks (2 per batch, 4/CU), restore
// launch_bounds(256,2); occupancy query verifies 4 blocks/CU co-residency
// before taking the cooperative path (else proven split fallback).
// Cross-block ws readback stays AGENT-scope atomic (R9 fix). Weights stay
// on the scalar path (R7 win). mask UNUSED (reference bug reproduced).

#define BB 512
#define TT 2048
#define DD 20
#define C0 32
#define C1 16

#define NTH 256               // 4 waves/block
#define NPOS 2                // positions per register round
#define POSB (NTH * NPOS)     // 512 positions per round
#define CHUNK 1024            // positions per block
#define NROUND (CHUNK / POSB) // 2 rounds
#define NBLK (TT / CHUNK)     // 2 blocks per batch
#define GRID (BB * NBLK)      // 1024 blocks
#define NSLOT 8               // atomic slot-split

// ws float offsets
#define WS_P1 0              // 8 slots * (32 sum + 32 sq)
#define WS_P2 512            // 8 slots * (16 sum + 16 sq)
#define WS_ZERO_N 768        // floats to zero each launch
#define WS_BLOB 896
#define BLOB_J 24            // 20 wM + c + pad
#define BLOB_B (C0 * BLOB_J) // 768 floats per batch

#define PIN(x) asm volatile("" : "+v"(x))
#define AGLOAD(p) \
    __hip_atomic_load((p), __ATOMIC_RELAXED, __HIP_MEMORY_SCOPE_AGENT)

__device__ __forceinline__ float fast_sigmoid(float x) {
    return __builtin_amdgcn_rcpf(1.0f + __expf(-x));
}

__device__ __forceinline__ void load_krow(const float* __restrict__ row,
                                          float* kk) {
    const float4* kr = (const float4*)row;  // rows are 80B => 16B aligned
    float4 a = kr[0], b = kr[1], c = kr[2], d = kr[3], e = kr[4];
    kk[0] = a.x; kk[1] = a.y; kk[2] = a.z; kk[3] = a.w;
    kk[4] = b.x; kk[5] = b.y; kk[6] = b.z; kk[7] = b.w;
    kk[8] = c.x; kk[9] = c.y; kk[10] = c.z; kk[11] = c.w;
    kk[12] = d.x; kk[13] = d.y; kk[14] = d.z; kk[15] = d.w;
    kk[16] = e.x; kk[17] = e.y; kk[18] = e.z; kk[19] = e.w;
}

// ---------------- prep: fold query into layer-1 weights ----------------
// Also zeroes the ws sums area and the output (replaces two memsets).
__global__ void prep_kernel(const float* __restrict__ query,
                            const float* __restrict__ W0,
                            const float* __restrict__ b0,
                            float* __restrict__ blob, float* __restrict__ ws,
                            float* __restrict__ out) {
    const int b = blockIdx.x * 2 + (threadIdx.x >> 5);
    const int j = threadIdx.x & 31;
    if (blockIdx.x == 0) {
        for (int i = threadIdx.x; i < WS_ZERO_N; i += 64) ws[i] = 0.f;
    }
    if (j < DD) out[b * DD + j] = 0.f;
    float cj = b0[j];
    float* dst = blob + (size_t)b * BLOB_B + j * BLOB_J;
#pragma unroll
    for (int d = 0; d < DD; ++d) {
        float w_q = W0[d * C0 + j];
        float w_k = W0[(DD + d) * C0 + j];
        float w_d = W0[(2 * DD + d) * C0 + j];
        float w_p = W0[(3 * DD + d) * C0 + j];
        float qd = query[b * DD + d];
        dst[d] = w_k - w_d + qd * w_p;
        cj = fmaf(qd, w_q + w_d, cj);
    }
    dst[20] = cj;
}

// Load NPOS key rows for round r and PIN them (defeat rematerialization).
#define LOAD_AND_PIN_KEYS(r)                                                 \
    float kk[NPOS][DD];                                                      \
    _Pragma("unroll") for (int pp = 0; pp < NPOS; ++pp)                      \
        load_krow(kbase + (size_t)((r)*POSB + tid + pp * NTH) * DD, kk[pp]); \
    _Pragma("unroll") for (int pp = 0; pp < NPOS; ++pp)                      \
        _Pragma("unroll") for (int d = 0; d < DD; ++d) PIN(kk[pp][d]);

// j-loop over 32 layer-1 channels. Weights on scalar path; scale/shift
// from LDS (uniform broadcast ds_read_b64).
#define TOWER_JLOOP()                                                        \
    _Pragma("unroll 1") for (int j = 0; j < C0; ++j) {                       \
        const float* wr = bA + j * BLOB_J;                                   \
        const float* ur = W1 + j * C1;                                       \
        const float cj = wr[20];                                             \
        const float2 ss = lss0[j];                                           \
        const float al = a0[j];                                              \
        const float nal = 1.0f - al;                                         \
        float h[NPOS];                                                       \
        _Pragma("unroll") for (int pp = 0; pp < NPOS; ++pp) {                \
            float hh = cj;                                                   \
            _Pragma("unroll") for (int d = 0; d < DD; ++d)                   \
                hh = fmaf(kk[pp][d], wr[d], hh);                             \
            h[pp] = hh;                                                      \
        }                                                                    \
        _Pragma("unroll") for (int pp = 0; pp < NPOS; ++pp) {                \
            float pr = fast_sigmoid(fmaf(h[pp], ss.x, ss.y));                \
            float h0d = h[pp] * fmaf(pr, nal, al);                           \
            _Pragma("unroll") for (int c = 0; c < C1; ++c)                   \
                h1[pp][c] = fmaf(h0d, ur[c], h1[pp][c]);                     \
        }                                                                    \
    }

// ================= shared phase bodies =================
__device__ __forceinline__ void phase1_body(int slot, int tid, int lane,
                                            const float* __restrict__ bA,
                                            const float* __restrict__ kbase,
                                            float* __restrict__ ws) {
    float s[C0], q[C0];
#pragma unroll
    for (int j = 0; j < C0; ++j) { s[j] = 0.f; q[j] = 0.f; }
#pragma unroll 1
    for (int r = 0; r < NROUND; ++r) {
        LOAD_AND_PIN_KEYS(r)
#pragma unroll
        for (int j = 0; j < C0; ++j) {
            const float* wr = bA + j * BLOB_J;  // uniform -> s_load
            const float cj = wr[20];
            float sv = 0.f, qv = 0.f;
#pragma unroll
            for (int pp = 0; pp < NPOS; ++pp) {
                float hh = cj;
#pragma unroll
                for (int d = 0; d < DD; ++d) hh = fmaf(kk[pp][d], wr[d], hh);
                sv += hh;
                qv = fmaf(hh, hh, qv);
            }
            s[j] += sv;
            q[j] += qv;
        }
    }
    float redv = 0.f;
#pragma unroll
    for (int v = 0; v < 2 * C0; ++v) {
        float val = (v < C0) ? s[v] : q[v - C0];
#pragma unroll
        for (int o = 32; o >= 1; o >>= 1) val += __shfl_xor(val, o);
        if (lane == v) redv = val;
    }
    atomicAdd(&ws[WS_P1 + slot * (2 * C0) + lane], redv);
}

__device__ __forceinline__ void finalize0(int tid, float* __restrict__ ws,
                                          float2* __restrict__ lss0) {
    if (tid < C0) {
        float sv = 0.f, qv = 0.f;
#pragma unroll
        for (int k = 0; k < NSLOT; ++k) {
            sv += AGLOAD(&ws[WS_P1 + k * (2 * C0) + tid]);
            qv += AGLOAD(&ws[WS_P1 + k * (2 * C0) + C0 + tid]);
        }
        const float invN = 1.0f / (float)(BB * TT);
        float mean = sv * invN;
        float var = qv * invN - mean * mean;
        float sc = rsqrtf(var + 1e-9f);
        lss0[tid] = make_float2(sc, -mean * sc);
    }
}

__device__ __forceinline__ void phase2_body(
    int slot, int tid, int lane, const float* __restrict__ bA,
    const float* __restrict__ kbase, const float* __restrict__ a0,
    const float* __restrict__ W1, const float* __restrict__ b1,
    const float2* __restrict__ lss0, float* __restrict__ ws) {
    float s1[C1], q1[C1];
#pragma unroll
    for (int c = 0; c < C1; ++c) { s1[c] = 0.f; q1[c] = 0.f; }
#pragma unroll 1
    for (int r = 0; r < NROUND; ++r) {
        LOAD_AND_PIN_KEYS(r)
        float h1[NPOS][C1];
#pragma unroll
        for (int pp = 0; pp < NPOS; ++pp)
#pragma unroll
            for (int c = 0; c < C1; ++c) h1[pp][c] = 0.f;
        TOWER_JLOOP()
#pragma unroll
        for (int c = 0; c < C1; ++c) {
            float bc = b1[c];
#pragma unroll
            for (int pp = 0; pp < NPOS; ++pp) {
                float v = h1[pp][c] + bc;
                s1[c] += v;
                q1[c] = fmaf(v, v, q1[c]);
            }
        }
    }
    float redv = 0.f;
#pragma unroll
    for (int v = 0; v < 2 * C1; ++v) {
        float val = (v < C1) ? s1[v] : q1[v - C1];
#pragma unroll
        for (int o = 32; o >= 1; o >>= 1) val += __shfl_xor(val, o);
        if (lane == v) redv = val;
    }
    if (lane < 2 * C1)
        atomicAdd(&ws[WS_P2 + slot * (2 * C1) + lane], redv);
}

__device__ __forceinline__ void finalize1(int tid, float* __restrict__ ws,
                                          const float* __restrict__ a1,
                                          const float* __restrict__ wk,
                                          float4* __restrict__ ld1v) {
    if (tid < C1) {
        float sv = 0.f, qv = 0.f;
#pragma unroll
        for (int k = 0; k < NSLOT; ++k) {
            sv += AGLOAD(&ws[WS_P2 + k * (2 * C1) + tid]);
            qv += AGLOAD(&ws[WS_P2 + k * (2 * C1) + C1 + tid]);
        }
        const float invN = 1.0f / (float)(BB * TT);
        float mean = sv * invN;
        float var = qv * invN - mean * mean;
        float sc = rsqrtf(var + 1e-9f);
        ld1v[tid] = make_float4(sc, -mean * sc, a1[tid], wk[tid]);
    }
}

__device__ __forceinline__ void phase3_body(
    int batch, int tid, int lane, int wave, const float* __restrict__ bA,
    const float* __restrict__ kbase, const float* __restrict__ a0,
    const float* __restrict__ W1, const float* __restrict__ b1,
    const float* __restrict__ bk, const float2* __restrict__ lss0,
    const float4* __restrict__ ld1v, float (*red)[DD],
    float* __restrict__ out) {
    const float bkv = bk[0];
    float oacc[DD];
#pragma unroll
    for (int d = 0; d < DD; ++d) oacc[d] = 0.f;
#pragma unroll 1
    for (int r = 0; r < NROUND; ++r) {
        LOAD_AND_PIN_KEYS(r)
        float h1[NPOS][C1];
#pragma unroll
        for (int pp = 0; pp < NPOS; ++pp)
#pragma unroll
            for (int c = 0; c < C1; ++c) h1[pp][c] = 0.f;
        TOWER_JLOOP()
#pragma unroll
        for (int pp = 0; pp < NPOS; ++pp) {
            float score = bkv;
#pragma unroll
            for (int c = 0; c < C1; ++c) {
                float v = h1[pp][c] + b1[c];
                float4 dv = ld1v[c];
                float pr = fast_sigmoid(fmaf(v, dv.x, dv.y));
                float hd = v * fmaf(pr, 1.0f - dv.z, dv.z);
                score = fmaf(hd, dv.w, score);
            }
#pragma unroll
            for (int d = 0; d < DD; ++d)
                oacc[d] = fmaf(score, kk[pp][d], oacc[d]);
        }
    }
    float redv = 0.f;
#pragma unroll
    for (int v = 0; v < DD; ++v) {
        float val = oacc[v];
#pragma unroll
        for (int o = 32; o >= 1; o >>= 1) val += __shfl_xor(val, o);
        if (lane == v) redv = val;
    }
    if (lane < DD) red[wave][lane] = redv;
    __syncthreads();
    if (tid < DD)
        atomicAdd(&out[batch * DD + tid],
                  red[0][tid] + red[1][tid] + red[2][tid] + red[3][tid]);
}

// ---------------- fused persistent kernel: all 3 passes ----------------
__global__ __launch_bounds__(NTH, 2) void fused_kernel(
    const float* __restrict__ keys, const float* __restrict__ blob,
    const float* __restrict__ a0, const float* __restrict__ W1,
    const float* __restrict__ b1, const float* __restrict__ a1,
    const float* __restrict__ wk, const float* __restrict__ bk,
    float* __restrict__ ws, float* __restrict__ out) {
    const int batch = blockIdx.x >> 1, chunk = blockIdx.x & 1;
    const int slot = blockIdx.x & (NSLOT - 1);
    const int tid = threadIdx.x, wave = tid >> 6, lane = tid & 63;
    const float* bA = blob + (size_t)batch * BLOB_B;
    const float* kbase = keys + ((size_t)batch * TT + chunk * CHUNK) * DD;

    __shared__ float2 lss0[C0];
    __shared__ float4 ld1v[C1];
    __shared__ float red[4][DD];

    phase1_body(slot, tid, lane, bA, kbase, ws);
    cg::this_grid().sync();
    finalize0(tid, ws, lss0);
    __syncthreads();
    phase2_body(slot, tid, lane, bA, kbase, a0, W1, b1, lss0, ws);
    cg::this_grid().sync();
    finalize1(tid, ws, a1, wk, ld1v);
    __syncthreads();
    phase3_body(batch, tid, lane, wave, bA, kbase, a0, W1, b1, bk, lss0,
                ld1v, red, out);
}

// ---------------- split fallback kernels ----------------
__global__ __launch_bounds__(NTH, 2) void pass1_kernel(
    const float* __restrict__ keys, const float* __restrict__ blob,
    float* __restrict__ ws) {
    const int batch = blockIdx.x >> 1, chunk = blockIdx.x & 1;
    const int tid = threadIdx.x, lane = tid & 63;
    phase1_body(blockIdx.x & (NSLOT - 1), tid, lane,
                blob + (size_t)batch * BLOB_B,
                keys + ((size_t)batch * TT + chunk * CHUNK) * DD, ws);
}

__global__ __launch_bounds__(NTH, 2) void pass2_kernel(
    const float* __restrict__ keys, const float* __restrict__ blob,
    const float* __restrict__ a0, const float* __restrict__ W1,
    const float* __restrict__ b1, float* __restrict__ ws) {
    const int batch = blockIdx.x >> 1, chunk = blockIdx.x & 1;
    const int tid = threadIdx.x, lane = tid & 63;
    __shared__ float2 lss0[C0];
    finalize0(tid, ws, lss0);
    __syncthreads();
    phase2_body(blockIdx.x & (NSLOT - 1), tid, lane,
                blob + (size_t)batch * BLOB_B,
                keys + ((size_t)batch * TT + chunk * CHUNK) * DD, a0, W1, b1,
                lss0, ws);
}

__global__ __launch_bounds__(NTH, 2) void pass3_kernel(
    const float* __restrict__ keys, const float* __restrict__ blob,
    const float* __restrict__ a0, const float* __restrict__ W1,
    const float* __restrict__ b1, const float* __restrict__ a1,
    const float* __restrict__ wk, const float* __restrict__ bk,
    float* __restrict__ ws, float* __restrict__ out) {
    const int batch = blockIdx.x >> 1, chunk = blockIdx.x & 1;
    const int tid = threadIdx.x, wave = tid >> 6, lane = tid & 63;
    __shared__ float2 lss0[C0];
    __shared__ float4 ld1v[C1];
    __shared__ float red[4][DD];
    finalize0(tid, ws, lss0);
    finalize1(tid, ws, a1, wk, ld1v);
    __syncthreads();
    phase3_body(batch, tid, lane, wave, blob + (size_t)batch * BLOB_B,
                keys + ((size_t)batch * TT + chunk * CHUNK) * DD, a0, W1, b1,
                bk, lss0, ld1v, red, out);
}

extern "C" void kernel_launch(void* const* d_in, const int* in_sizes, int n_in,
                              void* d_out, int out_size, void* d_ws,
                              size_t ws_size, hipStream_t stream) {
    const float* keys = (const float*)d_in[0];
    const float* query = (const float*)d_in[1];
    // d_in[2] = mask: intentionally unused
    const float* W0 = (const float*)d_in[3];
    const float* b0 = (const float*)d_in[4];
    const float* a0 = (const float*)d_in[5];
    const float* W1 = (const float*)d_in[6];
    const float* b1 = (const float*)d_in[7];
    const float* a1 = (const float*)d_in[8];
    const float* wk = (const float*)d_in[9];
    const float* bk = (const float*)d_in[10];
    float* out = (float*)d_out;
    float* ws = (float*)d_ws;
    float* blob = ws + WS_BLOB;  // 512*768 floats = 1.5 MB scratch
    const float* blobc = blob;

    // prep also zeroes ws sums + out (replaces both memsets)
    prep_kernel<<<BB / 2, 64, 0, stream>>>(query, W0, b0, blob, ws, out);

    // One-time host-side decision: is the 1024-block cooperative grid
    // guaranteed co-resident? (4 blocks/CU needs VGPR<=128; if the
    // allocator exceeded that, fall back to the split path.)
    static int use_coop = -1;
    if (use_coop < 0) {
        int nb = 0, ncu = 0;
        hipError_t e1 = hipOccupancyMaxActiveBlocksPerMultiprocessor(
            &nb, (const void*)fused_kernel, NTH, 0);
        hipDeviceProp_t prop;
        hipError_t e2 = hipGetDeviceProperties(&prop, 0);
        if (e2 == hipSuccess) ncu = prop.multiProcessorCount;
        use_coop = (e1 == hipSuccess && e2 == hipSuccess && nb * ncu >= GRID)
                       ? 1
                       : 0;
    }

    if (use_coop) {
        void* args[] = {(void*)&keys, (void*)&blobc, (void*)&a0, (void*)&W1,
                        (void*)&b1,   (void*)&a1,    (void*)&wk, (void*)&bk,
                        (void*)&ws,   (void*)&out};
        hipError_t e = hipLaunchCooperativeKernel(
            (const void*)fused_kernel, dim3(GRID), dim3(NTH), args, 0,
            stream);
        if (e != hipSuccess) use_coop = 0;  // record failed -> split path
    }
    if (!use_coop) {
        pass1_kernel<<<GRID, NTH, 0, stream>>>(keys, blob, ws);
        pass2_kernel<<<GRID, NTH, 0, stream>>>(keys, blob, a0, W1, b1, ws);
        pass3_kernel<<<GRID, NTH, 0, stream>>>(keys, blob, a0, W1, b1, a1, wk,
                                               bk, ws, out);
    }
}